// Round 10
// baseline (75.046 us; speedup 1.0000x reference)
//
#include <hip/hip_runtime.h>
#include <hip/hip_bf16.h>

#define F      128
#define NROWS  2048
#define MROWS  2048
#define BN     128         // n-rows per pair block
#define BM     64          // m-cols per pair block
#define MT     (MROWS/BM)  // 32 m-tiles
#define NCH    16          // 16 chunks of 8 g
#define LOG2E  1.44269504088896340736f

// LDS geometry: one row-chunk = 16 data floats (8 p0 | 8 p1) + 4 pad = 20 floats (80 B)
// stride 80 ≡ 16 (mod 128): 8 consecutive rows cover all 8 16B-slots -> R4's zero-conflict pattern
#define ROWF       20
#define AB_FLOATS  (BN * ROWF)           // 2560
#define BB_FLOATS  (BM * ROWF)           // 1280
#define BUF_FLOATS (AB_FLOATS + BB_FLOATS) // 3840 (15360 B)

typedef float f32x2 __attribute__((ext_vector_type(2)));
typedef float f32x4 __attribute__((ext_vector_type(4)));

__device__ __forceinline__ f32x2 lo2(f32x4 v) { return __builtin_shufflevector(v, v, 0, 1); }
__device__ __forceinline__ f32x2 hi2(f32x4 v) { return __builtin_shufflevector(v, v, 2, 3); }
__device__ __forceinline__ f32x2 pk_add(f32x2 a, f32x2 b) {
    f32x2 d; asm("v_pk_add_f32 %0, %1, %2" : "=v"(d) : "v"(a), "v"(b)); return d;
}
__device__ __forceinline__ f32x2 pk_mul(f32x2 a, f32x2 b) {
    f32x2 d; asm("v_pk_mul_f32 %0, %1, %2" : "=v"(d) : "v"(a), "v"(b)); return d;
}
__device__ __forceinline__ void gload16(const float* g, float* l) {
    __builtin_amdgcn_global_load_lds(
        (const __attribute__((address_space(1))) void*)g,
        (__attribute__((address_space(3))) void*)l, 16, 0, 0);
}

// --- Kernel 1: projections + ELU/w2 precompute + w2sum ----------------------
// a = (embeds@W1)[n][g], b = (base@W1)[m][g], w = w2[g]
// Global layout: P[row][ch][0..7]=plane0(g=ch*8+o), [8..15]=plane1 (256 f/row)
// PA: p0=(a+1)*w, p1=exp(a)*w ; PB: p0=-b*w, p1=exp(-b)
// w*elu(a-b) + w = med3(p0A + p0B, p1A * p1B, w)   [median commutes with *w, any sign]
__global__ __launch_bounds__(256) void proj_kernel(
    const float* __restrict__ embeds, const float* __restrict__ base,
    const float* __restrict__ W1, const float* __restrict__ w2,
    float* __restrict__ PA, float* __restrict__ PB,
    float* __restrict__ w2sum)
{
    const int tid = threadIdx.x;
    const int sub = tid >> 7;
    const int g   = tid & 127;
    const int row = blockIdx.x * 2 + sub;

    __shared__ float xs[2][F];
    {
        const float* src = (row < NROWS) ? &embeds[(size_t)row * F]
                                         : &base[(size_t)(row - NROWS) * F];
        xs[sub][g] = src[g];
    }
    __syncthreads();

    float acc = 0.0f;
#pragma unroll 8
    for (int f = 0; f < F; ++f)
        acc = fmaf(xs[sub][f], W1[f * F + g], acc);

    const float wv = w2[g];
    const int   ch = g >> 3, o = g & 7;
    if (row < NROWS) {
        float* dst = PA + (size_t)row * 256 + ch * 16 + o;
        dst[0] = (acc + 1.0f) * wv;
        dst[8] = __builtin_amdgcn_exp2f(acc * LOG2E) * wv;
    } else {
        float* dst = PB + (size_t)(row - NROWS) * 256 + ch * 16 + o;
        dst[0] = -acc * wv;
        dst[8] = __builtin_amdgcn_exp2f(-acc * LOG2E);
    }

    if (blockIdx.x == 0 && tid < 64) {
        float s = w2[tid] + w2[tid + 64];
#pragma unroll
        for (int k = 1; k < 64; k <<= 1) s += __shfl_xor(s, k);
        if (tid == 0) *w2sum = s;
    }
}

// --- Kernel 2: pair kernel -----------------------------------------------------
// grid (16,32), 256 threads; tile 128(n)x64(m); tr=tid>>4, tc=tid&15; Rn=8,Rm=4.
// Staging: 15 global_load_lds per chunk (A:10, B:5), DMA writes the PADDED LDS
// image (pad lanes re-fetch slot 0 of their row; dest is lane-linear as required).
// Compute reads: ds_read_b128 at thread-row base + compile-time imm offsets.
__global__ __launch_bounds__(256, 2) void pair_kernel(
    const float* __restrict__ PA, const float* __restrict__ PB,
    const float* __restrict__ w2, const float* __restrict__ w2sum_p,
    const float* __restrict__ brew, float* __restrict__ partials)
{
    __shared__ float sbuf[2 * BUF_FLOATS];   // 30720 B
    __shared__ float w2l[F];

    const int tid = threadIdx.x;
    const int wvi = tid >> 6, l = tid & 63;
    const int nt  = blockIdx.x, mt = blockIdx.y;
    const int n0  = nt * BN,    m0 = mt * BM;
    const int tr  = tid >> 4,   tc = tid & 15;

    // --- staging precompute: instr k = wvi + 4t; k<10 -> A panel, 10..14 -> B ---
    const float* ssrc[4];
    int sdst[4];
#pragma unroll
    for (int t = 0; t < 4; ++t) {
        const int k = wvi + 4 * t;
        int slot, dstf;
        const float* basep;
        if (k < 10) { slot = 64 * k + l;        dstf = k * 256;                    basep = PA + (size_t)n0 * 256; }
        else        { slot = 64 * (k - 10) + l; dstf = AB_FLOATS + (k - 10) * 256; basep = PB + (size_t)m0 * 256; }
        const int row = slot / 5;              // 5 x 16B slots per 80B LDS row
        const int rs  = slot - row * 5;        // 0..3 data, 4 = pad
        const int rsd = (rs == 4) ? 0 : rs;
        ssrc[t] = basep + row * 256 + rsd * 4; // chunk stride = 16 floats
        sdst[t] = dstf;
    }
    const bool has3 = (wvi < 3);   // wvi==3 -> k=15 invalid (only 15 instrs)

#define STAGE(CH, BUF) {                                                       \
    gload16(ssrc[0] + (CH) * 16, &sbuf[(BUF) * BUF_FLOATS + sdst[0]]);         \
    gload16(ssrc[1] + (CH) * 16, &sbuf[(BUF) * BUF_FLOATS + sdst[1]]);         \
    gload16(ssrc[2] + (CH) * 16, &sbuf[(BUF) * BUF_FLOATS + sdst[2]]);         \
    if (has3)                                                                   \
        gload16(ssrc[3] + (CH) * 16, &sbuf[(BUF) * BUF_FLOATS + sdst[3]]); }

    f32x2 acc2[8][4];
#pragma unroll
    for (int i = 0; i < 8; ++i)
#pragma unroll
        for (int j = 0; j < 4; ++j) acc2[i][j] = (f32x2)(0.0f);

    STAGE(0, 0)
    if (tid < F) w2l[tid] = w2[tid];
    __syncthreads();

#pragma unroll 1
    for (int ch = 0; ch < NCH; ++ch) {
        const int buf = ch & 1;
        if (ch + 1 < NCH) STAGE(ch + 1, buf ^ 1)

        const float* sa  = &sbuf[buf * BUF_FLOATS];
        const float* sbb = sa + AB_FLOATS;

#pragma unroll
        for (int h = 0; h < 2; ++h) {          // two 4-g halves of the 8-g chunk
            const f32x2 wlo = *(const f32x2*)&w2l[ch * 8 + h * 4];
            const f32x2 whi = *(const f32x2*)&w2l[ch * 8 + h * 4 + 2];
            f32x4 b1v[4], bev[4];
#pragma unroll
            for (int j = 0; j < 4; ++j) {
                const float* bp = sbb + (tc + 16 * j) * ROWF + h * 4;
                b1v[j] = *(const f32x4*)bp;
                bev[j] = *(const f32x4*)(bp + 8);
            }
#pragma unroll
            for (int i = 0; i < 8; ++i) {
                const float* ap = sa + (tr + 16 * i) * ROWF + h * 4;
                const f32x4 a1 = *(const f32x4*)ap;
                const f32x4 ae = *(const f32x4*)(ap + 8);
                const f32x2 a1l = lo2(a1), a1h = hi2(a1);
                const f32x2 ael = lo2(ae), aeh = hi2(ae);
#pragma unroll
                for (int j = 0; j < 4; ++j) {
                    const f32x2 xl = pk_add(a1l, lo2(b1v[j]));
                    const f32x2 el = pk_mul(ael, lo2(bev[j]));
                    const f32x2 xh = pk_add(a1h, hi2(b1v[j]));
                    const f32x2 eh = pk_mul(aeh, hi2(bev[j]));
                    f32x2 sl, sh;
                    sl.x = __builtin_amdgcn_fmed3f(xl.x, el.x, wlo.x);
                    sl.y = __builtin_amdgcn_fmed3f(xl.y, el.y, wlo.y);
                    sh.x = __builtin_amdgcn_fmed3f(xh.x, eh.x, whi.x);
                    sh.y = __builtin_amdgcn_fmed3f(xh.y, eh.y, whi.y);
                    acc2[i][j] = pk_add(acc2[i][j], pk_add(sl, sh));
                }
            }
        }
        __syncthreads();   // all waves done reading buf; stage into buf landed
    }
#undef STAGE

    const float w2sum = *w2sum_p;
    float rsv[4];
#pragma unroll
    for (int j = 0; j < 4; ++j) rsv[j] = brew[m0 + tc + 16 * j];

#pragma unroll
    for (int i = 0; i < 8; ++i) {
        float sw = 0.0f, swr = 0.0f;
#pragma unroll
        for (int j = 0; j < 4; ++j) {
            const float tot  = acc2[i][j].x + acc2[i][j].y;
            const float dist = fabsf(tot - w2sum);
            const float wgt  = 1.0f / (dist + 1e-4f);
            sw += wgt;
            swr = fmaf(wgt, rsv[j], swr);
        }
#pragma unroll
        for (int k = 1; k < 16; k <<= 1) {   // reduce over tc (low 4 lane bits)
            sw  += __shfl_xor(sw, k);
            swr += __shfl_xor(swr, k);
        }
        if (tc == 0) {
            const int n = n0 + tr + 16 * i;
            partials[((size_t)n * MT + mt) * 2 + 0] = sw;
            partials[((size_t)n * MT + mt) * 2 + 1] = swr;
        }
    }
}

// --- Kernel 3: reduce tile partials, divide ------------------------------------
__global__ __launch_bounds__(256) void finalize_kernel(
    const float* __restrict__ partials, float* __restrict__ out)
{
    const int n = blockIdx.x * 256 + threadIdx.x;
    if (n < NROWS) {
        float sw = 0.0f, swr = 0.0f;
#pragma unroll
        for (int t = 0; t < MT; ++t) {
            sw  += partials[((size_t)n * MT + t) * 2 + 0];
            swr += partials[((size_t)n * MT + t) * 2 + 1];
        }
        out[n] = swr / sw;
    }
}

extern "C" void kernel_launch(void* const* d_in, const int* in_sizes, int n_in,
                              void* d_out, int out_size, void* d_ws, size_t ws_size,
                              hipStream_t stream)
{
    const float* embeds       = (const float*)d_in[0];  // [2048,128]
    const float* base_embeds  = (const float*)d_in[1];  // [2048,128]
    const float* base_rewards = (const float*)d_in[2];  // [2048]
    const float* W1           = (const float*)d_in[3];  // [128,128] (in,out)
    const float* w2           = (const float*)d_in[4];  // [128,1]
    float* out = (float*)d_out;

    // ws: partials [2048*MT*2] | PA [2048*256] | PB [2048*256] | w2sum[1]
    float* partials = (float*)d_ws;
    float* PA  = partials + (size_t)NROWS * MT * 2;
    float* PB  = PA + (size_t)NROWS * 256;
    float* w2s = PB + (size_t)MROWS * 256;

    proj_kernel<<<(NROWS + MROWS) / 2, 256, 0, stream>>>(
        embeds, base_embeds, W1, w2, PA, PB, w2s);

    dim3 grid2(NROWS / BN, MROWS / BM);
    pair_kernel<<<grid2, 256, 0, stream>>>(PA, PB, w2, w2s, base_rewards, partials);

    finalize_kernel<<<(NROWS + 255) / 256, 256, 0, stream>>>(partials, out);
}

// Round 11
// 74.353 us; speedup vs baseline: 1.0093x; 1.0093x over previous
//
#include <hip/hip_runtime.h>
#include <hip/hip_bf16.h>

#define F      128
#define NROWS  2048
#define MROWS  2048
#define BN     128         // n-rows per pair block
#define BM     64          // m-cols per pair block
#define MT     (MROWS/BM)  // 32 m-tiles
#define NCH    16          // 16 chunks of 8 g
#define LOG2E  1.44269504088896340736f

// LDS geometry: one row-chunk = 16 data floats (8 p0 | 8 p1) + 4 pad = 20 floats (80 B)
// stride 80 ≡ 16 (mod 128): measured zero-conflict pattern (R10)
#define ROWF       20
#define AB_FLOATS  (BN * ROWF)             // 2560
#define BB_FLOATS  (BM * ROWF)             // 1280
#define BUF_FLOATS (AB_FLOATS + BB_FLOATS) // 3840 (15360 B)

typedef float f32x2 __attribute__((ext_vector_type(2)));
typedef float f32x4 __attribute__((ext_vector_type(4)));

__device__ __forceinline__ f32x2 lo2(f32x4 v) { return __builtin_shufflevector(v, v, 0, 1); }
__device__ __forceinline__ f32x2 hi2(f32x4 v) { return __builtin_shufflevector(v, v, 2, 3); }
__device__ __forceinline__ void gload16(const float* g, float* l) {
    __builtin_amdgcn_global_load_lds(
        (const __attribute__((address_space(1))) void*)g,
        (__attribute__((address_space(3))) void*)l, 16, 0, 0);
}

// --- Kernel 1: projections + ELU/w2 precompute + w2sum ----------------------
// a = (embeds@W1)[n][g], b = (base@W1)[m][g], w = w2[g]
// Global layout: P[row][ch][0..7]=plane0(g=ch*8+o), [8..15]=plane1 (256 f/row)
// PA: p0=(a+1)*w, p1=exp(a)*w ; PB: p0=-b*w, p1=exp(-b)
// w*elu(a-b) + w = med3(p0A + p0B, p1A * p1B, w)   [median commutes with *w, any sign]
__global__ __launch_bounds__(256) void proj_kernel(
    const float* __restrict__ embeds, const float* __restrict__ base,
    const float* __restrict__ W1, const float* __restrict__ w2,
    float* __restrict__ PA, float* __restrict__ PB,
    float* __restrict__ w2sum)
{
    const int tid = threadIdx.x;
    const int sub = tid >> 7;
    const int g   = tid & 127;
    const int row = blockIdx.x * 2 + sub;

    __shared__ float xs[2][F];
    {
        const float* src = (row < NROWS) ? &embeds[(size_t)row * F]
                                         : &base[(size_t)(row - NROWS) * F];
        xs[sub][g] = src[g];
    }
    __syncthreads();

    float acc = 0.0f;
#pragma unroll 8
    for (int f = 0; f < F; ++f)
        acc = fmaf(xs[sub][f], W1[f * F + g], acc);

    const float wv = w2[g];
    const int   ch = g >> 3, o = g & 7;
    if (row < NROWS) {
        float* dst = PA + (size_t)row * 256 + ch * 16 + o;
        dst[0] = (acc + 1.0f) * wv;
        dst[8] = __builtin_amdgcn_exp2f(acc * LOG2E) * wv;
    } else {
        float* dst = PB + (size_t)(row - NROWS) * 256 + ch * 16 + o;
        dst[0] = -acc * wv;
        dst[8] = __builtin_amdgcn_exp2f(-acc * LOG2E);
    }

    if (blockIdx.x == 0 && tid < 64) {
        float s = w2[tid] + w2[tid + 64];
#pragma unroll
        for (int k = 1; k < 64; k <<= 1) s += __shfl_xor(s, k);
        if (tid == 0) *w2sum = s;
    }
}

// --- Kernel 2: pair kernel -----------------------------------------------------
// grid (16,32), 256 threads; tile 128(n)x64(m); tr=tid>>4, tc=tid&15; Rn=8,Rm=4.
// Staging identical to R10 (global_load_lds into padded rows, double-buffered,
// one barrier per chunk). Inner math: plain-C f32x2 (v_pk_add/mul_f32 codegen)
// + scalar v_med3 + scalar accumulate: 11 VALU / 4 elem-g.
__global__ __launch_bounds__(256, 2) void pair_kernel(
    const float* __restrict__ PA, const float* __restrict__ PB,
    const float* __restrict__ w2, const float* __restrict__ w2sum_p,
    const float* __restrict__ brew, float* __restrict__ partials)
{
    __shared__ float sbuf[2 * BUF_FLOATS];   // 30720 B
    __shared__ float w2l[F];

    const int tid = threadIdx.x;
    const int wvi = tid >> 6, l = tid & 63;
    const int nt  = blockIdx.x, mt = blockIdx.y;
    const int n0  = nt * BN,    m0 = mt * BM;
    const int tr  = tid >> 4,   tc = tid & 15;

    // --- staging precompute: instr k = wvi + 4t; k<10 -> A panel, 10..14 -> B ---
    const float* ssrc[4];
    int sdst[4];
#pragma unroll
    for (int t = 0; t < 4; ++t) {
        const int k = wvi + 4 * t;
        int slot, dstf;
        const float* basep;
        if (k < 10) { slot = 64 * k + l;        dstf = k * 256;                    basep = PA + (size_t)n0 * 256; }
        else        { slot = 64 * (k - 10) + l; dstf = AB_FLOATS + (k - 10) * 256; basep = PB + (size_t)m0 * 256; }
        const int row = slot / 5;              // 5 x 16B slots per 80B LDS row
        const int rs  = slot - row * 5;        // 0..3 data, 4 = pad
        const int rsd = (rs == 4) ? 0 : rs;
        ssrc[t] = basep + row * 256 + rsd * 4; // chunk stride = 16 floats
        sdst[t] = dstf;
    }
    const bool has3 = (wvi < 3);   // wvi==3 -> k=15 invalid (only 15 instrs)

#define STAGE(CH, BUF) {                                                       \
    gload16(ssrc[0] + (CH) * 16, &sbuf[(BUF) * BUF_FLOATS + sdst[0]]);         \
    gload16(ssrc[1] + (CH) * 16, &sbuf[(BUF) * BUF_FLOATS + sdst[1]]);         \
    gload16(ssrc[2] + (CH) * 16, &sbuf[(BUF) * BUF_FLOATS + sdst[2]]);         \
    if (has3)                                                                   \
        gload16(ssrc[3] + (CH) * 16, &sbuf[(BUF) * BUF_FLOATS + sdst[3]]); }

    float acc[8][4];
#pragma unroll
    for (int i = 0; i < 8; ++i)
#pragma unroll
        for (int j = 0; j < 4; ++j) acc[i][j] = 0.0f;

    STAGE(0, 0)
    if (tid < F) w2l[tid] = w2[tid];
    __syncthreads();

#pragma unroll 1
    for (int ch = 0; ch < NCH; ++ch) {
        const int buf = ch & 1;
        if (ch + 1 < NCH) STAGE(ch + 1, buf ^ 1)

        const float* sa  = &sbuf[buf * BUF_FLOATS];
        const float* sbb = sa + AB_FLOATS;

#pragma unroll
        for (int h = 0; h < 2; ++h) {          // two 4-g halves of the 8-g chunk
            const float wq0 = w2l[ch * 8 + h * 4 + 0];
            const float wq1 = w2l[ch * 8 + h * 4 + 1];
            const float wq2 = w2l[ch * 8 + h * 4 + 2];
            const float wq3 = w2l[ch * 8 + h * 4 + 3];
            f32x4 b1v[4], bev[4];
#pragma unroll
            for (int j = 0; j < 4; ++j) {
                const float* bp = sbb + (tc + 16 * j) * ROWF + h * 4;
                b1v[j] = *(const f32x4*)bp;
                bev[j] = *(const f32x4*)(bp + 8);
            }
#pragma unroll
            for (int i = 0; i < 8; ++i) {
                const float* ap = sa + (tr + 16 * i) * ROWF + h * 4;
                const f32x4 a1 = *(const f32x4*)ap;
                const f32x4 ae = *(const f32x4*)(ap + 8);
                const f32x2 a1l = lo2(a1), a1h = hi2(a1);
                const f32x2 ael = lo2(ae), aeh = hi2(ae);
#pragma unroll
                for (int j = 0; j < 4; ++j) {
                    const f32x2 xl = a1l + lo2(b1v[j]);   // v_pk_add_f32
                    const f32x2 xh = a1h + hi2(b1v[j]);
                    const f32x2 el = ael * lo2(bev[j]);   // v_pk_mul_f32
                    const f32x2 eh = aeh * hi2(bev[j]);
                    const float s0 = __builtin_amdgcn_fmed3f(xl.x, el.x, wq0);
                    const float s1 = __builtin_amdgcn_fmed3f(xl.y, el.y, wq1);
                    const float s2 = __builtin_amdgcn_fmed3f(xh.x, eh.x, wq2);
                    const float s3 = __builtin_amdgcn_fmed3f(xh.y, eh.y, wq3);
                    acc[i][j] += (s0 + s1) + (s2 + s3);
                }
            }
        }
        __syncthreads();   // all waves done reading buf; stage into buf landed
    }
#undef STAGE

    const float w2sum = *w2sum_p;
    float rsv[4];
#pragma unroll
    for (int j = 0; j < 4; ++j) rsv[j] = brew[m0 + tc + 16 * j];

#pragma unroll
    for (int i = 0; i < 8; ++i) {
        float sw = 0.0f, swr = 0.0f;
#pragma unroll
        for (int j = 0; j < 4; ++j) {
            const float dist = fabsf(acc[i][j] - w2sum);
            const float wgt  = 1.0f / (dist + 1e-4f);
            sw += wgt;
            swr = fmaf(wgt, rsv[j], swr);
        }
#pragma unroll
        for (int k = 1; k < 16; k <<= 1) {   // reduce over tc (low 4 lane bits)
            sw  += __shfl_xor(sw, k);
            swr += __shfl_xor(swr, k);
        }
        if (tc == 0) {
            const int n = n0 + tr + 16 * i;
            partials[((size_t)n * MT + mt) * 2 + 0] = sw;
            partials[((size_t)n * MT + mt) * 2 + 1] = swr;
        }
    }
}

// --- Kernel 3: reduce tile partials, divide ------------------------------------
__global__ __launch_bounds__(256) void finalize_kernel(
    const float* __restrict__ partials, float* __restrict__ out)
{
    const int n = blockIdx.x * 256 + threadIdx.x;
    if (n < NROWS) {
        float sw = 0.0f, swr = 0.0f;
#pragma unroll
        for (int t = 0; t < MT; ++t) {
            sw  += partials[((size_t)n * MT + t) * 2 + 0];
            swr += partials[((size_t)n * MT + t) * 2 + 1];
        }
        out[n] = swr / sw;
    }
}

extern "C" void kernel_launch(void* const* d_in, const int* in_sizes, int n_in,
                              void* d_out, int out_size, void* d_ws, size_t ws_size,
                              hipStream_t stream)
{
    const float* embeds       = (const float*)d_in[0];  // [2048,128]
    const float* base_embeds  = (const float*)d_in[1];  // [2048,128]
    const float* base_rewards = (const float*)d_in[2];  // [2048]
    const float* W1           = (const float*)d_in[3];  // [128,128] (in,out)
    const float* w2           = (const float*)d_in[4];  // [128,1]
    float* out = (float*)d_out;

    // ws: partials [2048*MT*2] | PA [2048*256] | PB [2048*256] | w2sum[1]
    float* partials = (float*)d_ws;
    float* PA  = partials + (size_t)NROWS * MT * 2;
    float* PB  = PA + (size_t)NROWS * 256;
    float* w2s = PB + (size_t)MROWS * 256;

    proj_kernel<<<(NROWS + MROWS) / 2, 256, 0, stream>>>(
        embeds, base_embeds, W1, w2, PA, PB, w2s);

    dim3 grid2(NROWS / BN, MROWS / BM);
    pair_kernel<<<grid2, 256, 0, stream>>>(PA, PB, w2, w2s, base_rewards, partials);

    finalize_kernel<<<(NROWS + 255) / 256, 256, 0, stream>>>(partials, out);
}